// Round 16
// baseline (129.661 us; speedup 1.0000x reference)
//
#include <hip/hip_runtime.h>

#define WF 512
#define HF 256
#define CF 64
#define NDTOT 65
#define DP 72            // padded d-stride in ws (f16 elements), 144 B rows
#define APAD 40          // padded ch-stride (f16) of LDS col-major tiles

static constexpr size_t CH  = (size_t)HF * WF;
static constexpr size_t WH  = (size_t)HF * WF;
static constexpr float  INV = 1.0f / 576.0f;

typedef _Float16 f16;
typedef _Float16 f16x2 __attribute__((ext_vector_type(2)));
typedef _Float16 f16x4 __attribute__((ext_vector_type(4)));
typedef _Float16 f16x8 __attribute__((ext_vector_type(8)));
typedef float    f32x4 __attribute__((ext_vector_type(4)));

// ---------------------------------------------------------------------------
// k1 (R16): banded Gram via MFMA, SINGLE f16 (hi/lo dropped — error budget
// ~1.5e-4 conversion + ~1e-3 ws-f16 < 4.8e-3 threshold), m97-canonical shape.
// Block = (b, y, 128-col strip), 4 waves. Per 32-ch half:
//   - cooperative CONTIGUOUS f32x4 row-major loads (A: 128 cols, B: 192 cols
//     incl. +-32 halo, OOB zeroed at staging) — box/m13-style burst pattern,
//     replacing the scattered-64B-segment reads of R6-R15;
//   - f16 convert in regs, transpose-write to col-major LDS [col][APAD];
//   - frags = single ds_read_b128 (f16x8, K=32); 10 MFMA/wave/half.
// T14: next half's loads issued before current half's compute.
// Band mapping d=16p+n-m, frag layout, epilogue: validated R5-R15.
// ---------------------------------------------------------------------------
__global__ __launch_bounds__(256, 2)
void corr_gram(const float* __restrict__ x0, const float* __restrict__ x1,
               f16* __restrict__ ws) {
    // XCD swizzle (bijective, nwg%8==0): strips of one (b,y) adjacent per XCD.
    const int f = blockIdx.x;              // [0, 4096)
    const int xcd = f & 7;
    const int strip = (f >> 3) & 3;
    const int pl = f >> 5;                 // [0, 128)
    const int pair = xcd * 128 + pl;       // [0, 1024)
    const int y = pair & 255;
    const int b = pair >> 8;

    const int t = threadIdx.x;
    const int l = t & 63;
    const int w = t >> 6;
    const int X0 = strip << 7;             // block col base
    const int jb = X0 - 32;                // B window base (192 cols)

    const int n  = l & 15;                 // fragment row/col
    const int kq = l >> 4;                 // fragment k-quad (8 ch per frag)

    __shared__ f16 S[12800];               // 25.6 KB: SA [0,5120), SB [5120,12800)
    f16* SA = S;                           // [128 col][APAD ch]
    f16* SB = S + 5120;                    // [192 col][APAD ch]

    const float* x0r = x0 + (size_t)b * CF * CH + (size_t)y * WF;
    const float* x1r = x1 + (size_t)b * CF * CH + (size_t)y * WF;

    // ---- staging indices (lane-constant) ----
    const int c4  = t & 31;                // A col-group: cols 4c4..4c4+3
    const int chq = t >> 5;                // A ch-quad:  ch 4chq..4chq+3
    int bchp[3], bc4b[3], bcol[3]; bool bok[3];
#pragma unroll
    for (int u = 0; u < 3; ++u) {
        const int idx = u * 256 + t;       // [0, 768) = 16 chpairs x 48 colgroups
        bchp[u] = idx / 48;
        bc4b[u] = idx - 48 * bchp[u];
        bcol[u] = jb + 4 * bc4b[u];
        bok[u]  = (unsigned)bcol[u] < (unsigned)WF;
    }

#define LOADH(h, A4, B4) do { \
    const float* xa = x0r + (size_t)((h) * 32 + 4 * chq) * CH + (X0 + 4 * c4); \
    _Pragma("unroll") \
    for (int j = 0; j < 4; ++j) A4[j] = *(const f32x4*)(xa + (size_t)j * CH); \
    _Pragma("unroll") \
    for (int u = 0; u < 3; ++u) { \
        const float* xb = x1r + (size_t)((h) * 32 + 2 * bchp[u]) * CH + bcol[u]; \
        B4[2*u]     = bok[u] ? *(const f32x4*)xb        : (f32x4)0.f; \
        B4[2*u + 1] = bok[u] ? *(const f32x4*)(xb + CH) : (f32x4)0.f; \
    } \
} while (0)

#define CVTW(A4, B4) do { \
    _Pragma("unroll") \
    for (int j2 = 0; j2 < 4; ++j2) { \
        f16x4 v; \
        v[0] = (f16)A4[0][j2]; v[1] = (f16)A4[1][j2]; \
        v[2] = (f16)A4[2][j2]; v[3] = (f16)A4[3][j2]; \
        *(f16x4*)&SA[(4 * c4 + j2) * APAD + 4 * chq] = v; \
    } \
    _Pragma("unroll") \
    for (int u = 0; u < 3; ++u) { \
        _Pragma("unroll") \
        for (int j2 = 0; j2 < 4; ++j2) { \
            f16x2 v; \
            v[0] = (f16)B4[2*u][j2]; v[1] = (f16)B4[2*u + 1][j2]; \
            *(f16x2*)&SB[(4 * bc4b[u] + j2) * APAD + 2 * bchp[u]] = v; \
        } \
    } \
} while (0)

#define COMP() do { \
    const f16x8 a0 = *(const f16x8*)&SA[(w * 32 + n) * APAD + kq * 8]; \
    const f16x8 a1 = *(const f16x8*)&SA[(w * 32 + 16 + n) * APAD + kq * 8]; \
    _Pragma("unroll") \
    for (int jt = 0; jt < 6; ++jt) { \
        const f16x8 bf = *(const f16x8*)&SB[(w * 32 + jt * 16 + n) * APAD + kq * 8]; \
        if (jt < 5) \
            acc[jt] = __builtin_amdgcn_mfma_f32_16x16x32_f16(a0, bf, acc[jt], 0, 0, 0); \
        if (jt >= 1) \
            acc[4 + jt] = __builtin_amdgcn_mfma_f32_16x16x32_f16(a1, bf, acc[4 + jt], 0, 0, 0); \
    } \
} while (0)

    f32x4 acc[10];
#pragma unroll
    for (int i = 0; i < 10; ++i) acc[i] = (f32x4)0.0f;

    f32x4 a4[4], b4[6], a4n[4], b4n[6];

    LOADH(0, a4, b4);
    CVTW(a4, b4);
    __syncthreads();                       // half 0 staged
    LOADH(1, a4n, b4n);                    // T14: in flight during compute
    COMP();                                // half 0
    __syncthreads();                       // all reads done
    CVTW(a4n, b4n);
    __syncthreads();                       // half 1 staged
    COMP();                                // half 1
    __syncthreads();                       // LDS free for epilogue reuse

#undef COMP
#undef CVTW
#undef LOADH

    // ---- epilogue (wave-private): scatter band to LDS, coalesced stores ----
    f16* eb = S + w * 2304;                // [32 col][72 d] f16 = 4608 B
#pragma unroll
    for (int xt = 0; xt < 2; ++xt) {
#pragma unroll
        for (int p = 0; p < 5; ++p) {
            const int i = xt * 5 + p;
#pragma unroll
            for (int q = 0; q < 4; ++q) {
                const int m = kq * 4 + q;
                const int xl = xt * 16 + m;
                const int d = 16 * p + n - m;
                if ((unsigned)d < (unsigned)NDTOT)
                    eb[xl * DP + d] = (f16)acc[i][q];
            }
        }
    }
    // zero pad columns d=65..71 (32 x 7 = 224 entries)
#pragma unroll
    for (int i = 0; i < 4; ++i) {
        const int idx = l + 64 * i;
        if (idx < 224) {
            const int xl = idx / 7;
            eb[xl * DP + NDTOT + (idx - 7 * xl)] = (f16)0.f;
        }
    }
    // coalesced store: 32*72 f16 = 4608 B = 288 x 16B chunks
    uint4* dst = (uint4*)(ws + ((size_t)(b * HF + y) * WF + X0 + w * 32) * DP);
    const uint4* src = (const uint4*)eb;
#pragma unroll
    for (int i = 0; i < 5; ++i) {
        const int idx = l + 64 * i;
        if (idx < 288) dst[idx] = src[idx];
    }
}

// ---------------------------------------------------------------------------
// k2: 3x3 box-sum over ws + scale: out[b,d,y,x] = INV * sum_{3x3} ws[y+dy][x+dx][d]
// grid (16 x-tiles of 32, 32 y-tiles of 8, b); 256 thr.
// ---------------------------------------------------------------------------
__global__ __launch_bounds__(256)
void corr_box(const f16* __restrict__ ws, float* __restrict__ out) {
    const int xt = blockIdx.x;
    const int yt = blockIdx.y;
    const int b = blockIdx.z;
    const int t = threadIdx.x;
    const int x0b = xt * 32, y0 = yt * 8;

    __shared__ f16 S[10 * 34][DP];     // 48.96 KB

    for (int u = 0; u < 10; ++u) {
        const int yy = y0 - 1 + u;
        const bool yok = (unsigned)yy < (unsigned)HF;
        const f16* src = ws + ((size_t)(b * HF + yy) * WF + (x0b - 1)) * DP;
#pragma unroll
        for (int sub = 0; sub < 2; ++sub) {
            const int idx = sub * 256 + t;
            if (idx < 306) {
                const int v = idx / 9, dg = idx - v * 9;
                const int xx = x0b - 1 + v;
                f16x8 val;
#pragma unroll
                for (int jj = 0; jj < 8; ++jj) val[jj] = (f16)0.f;
                if (yok && (unsigned)xx < (unsigned)WF)
                    val = *(const f16x8*)(src + (size_t)v * DP + dg * 8);
                *(f16x8*)&S[u * 34 + v][dg * 8] = val;
            }
        }
    }
    __syncthreads();

    const int ly = t >> 5, lx = t & 31;
    const int yg = y0 + ly, xg = x0b + lx;
    float* o0 = out + (size_t)b * NDTOT * WH + (size_t)yg * WF + xg;

#pragma unroll 1
    for (int dg = 0; dg < 9; ++dg) {
        f16x8 s;
#pragma unroll
        for (int jj = 0; jj < 8; ++jj) s[jj] = (f16)0.f;
#pragma unroll
        for (int du = 0; du < 3; ++du)
#pragma unroll
            for (int dv = 0; dv < 3; ++dv)
                s += *(const f16x8*)&S[(ly + du) * 34 + (lx + dv)][dg * 8];
#pragma unroll
        for (int jj = 0; jj < 8; ++jj) {
            const int d = dg * 8 + jj;
            if (d < NDTOT) o0[(size_t)d * WH] = (float)s[jj] * INV;
        }
    }
}

// ---------------------------------------------------------------------------
// Emergency fallback (tiny ws): direct computation, slow but correct.
// ---------------------------------------------------------------------------
__global__ void corr_naive(const float* __restrict__ x0, const float* __restrict__ x1,
                           float* __restrict__ out) {
    const size_t total = (size_t)4 * NDTOT * WH;
    size_t idx = (size_t)blockIdx.x * blockDim.x + threadIdx.x;
    if (idx >= total) return;
    const int j = (int)(idx % WF);
    const int i = (int)((idx / WF) % HF);
    const int d = (int)((idx / WH) % NDTOT);
    const int b = (int)(idx / ((size_t)NDTOT * WH));
    const int disp = d - 32;
    float s = 0.f;
    for (int u = i - 1; u <= i + 1; ++u) {
        if (u < 0 || u >= HF) continue;
        for (int v = j - 1; v <= j + 1; ++v) {
            if (v < 0 || v >= WF) continue;
            const int v1c = v + disp;
            if (v1c < 0 || v1c >= WF) continue;
            const float* p0 = x0 + (size_t)b * CF * CH + (size_t)u * WF + v;
            const float* p1 = x1 + (size_t)b * CF * CH + (size_t)u * WF + v1c;
            for (int c = 0; c < CF; ++c)
                s += p0[(size_t)c * CH] * p1[(size_t)c * CH];
        }
    }
    out[idx] = s * INV;
}

// ---------------------------------------------------------------------------
extern "C" void kernel_launch(void* const* d_in, const int* in_sizes, int n_in,
                              void* d_out, int out_size, void* d_ws, size_t ws_size,
                              hipStream_t stream) {
    const float* x0 = (const float*)d_in[0];
    const float* x1 = (const float*)d_in[1];
    float* out = (float*)d_out;

    const size_t wsNeed = (size_t)4 * HF * WF * DP * sizeof(f16);  // 75.5 MB

    if (ws_size >= wsNeed) {
        f16* ws = (f16*)d_ws;
        corr_gram<<<dim3(4096), dim3(256), 0, stream>>>(x0, x1, ws);
        corr_box<<<dim3(16, 32, 4), dim3(256), 0, stream>>>(ws, out);
    } else {
        const size_t total = (size_t)4 * NDTOT * WH;
        const int blocks = (int)((total + 255) / 256);
        corr_naive<<<dim3(blocks), dim3(256), 0, stream>>>(x0, x1, out);
    }
}